// Round 1
// baseline (898.729 us; speedup 1.0000x reference)
//
#include <hip/hip_runtime.h>

// LLM block: B=2,S=2048,D=2048,H=16,KVH=8,HD=128,FF=5504, f32 in/out, bf16 MFMA compute.
// Workspace layout (bytes), peak ~131MB:
//   A wqkv_bf16   [4096,2048]  @ 0
//   B h/h2_bf16   [4096,2048]  @ 16777216
//   C qkv_bf16    [4096,4096]  @ 33554432   (reused later by wgu)
//   D attn_out    [4096,2048]  @ 67108864
//   E wo_bf16     [2048,2048]  @ 83886080
//   G wgu_bf16    [11008,2048] @ 33554432
//   H act_bf16    [4096,5504]  @ 92274688
//   I wdown_bf16  [2048,5504]  @ 0
//   x1 (f32 residual) lives in d_out.

#define DM 2048
#define TOK 4096
#define SEQ 2048
#define NH 16
#define HD 128
#define FF_ 5504
#define QK_SCALE 0.08838834764831845f

typedef __bf16 bf16x8 __attribute__((ext_vector_type(8)));
typedef float f32x4 __attribute__((ext_vector_type(4)));
typedef unsigned short u16x8 __attribute__((ext_vector_type(8)));

typedef __attribute__((address_space(1))) void* gas1;
typedef __attribute__((address_space(3))) void* las3;
#define GLDS16(g, s) __builtin_amdgcn_global_load_lds((gas1)(g), (las3)(s), 16, 0, 0)

static __device__ __forceinline__ float bf2f(unsigned short u) {
  union { unsigned int i; float f; } c; c.i = ((unsigned int)u) << 16; return c.f;
}
static __device__ __forceinline__ unsigned short f2bf(float f) {
  __bf16 b = (__bf16)f;
  return __builtin_bit_cast(unsigned short, b);
}

// ---------------- f32 -> bf16 convert (8 elems/thread, exact grid) ----------------
__global__ __launch_bounds__(256) void k_conv(const float* __restrict__ src,
                                              unsigned short* __restrict__ dst) {
  size_t i = (size_t)(blockIdx.x * 256 + threadIdx.x) * 8;
  float4 a = *(const float4*)&src[i];
  float4 b = *(const float4*)&src[i + 4];
  u16x8 o;
  o[0] = f2bf(a.x); o[1] = f2bf(a.y); o[2] = f2bf(a.z); o[3] = f2bf(a.w);
  o[4] = f2bf(b.x); o[5] = f2bf(b.y); o[6] = f2bf(b.z); o[7] = f2bf(b.w);
  *(u16x8*)&dst[i] = o;
}

// ---------------- RMSNorm: one block per row (D=2048, 8 f32/thread) ----------------
__global__ __launch_bounds__(256) void k_rmsnorm(const float* __restrict__ x,
                                                 const float* __restrict__ g,
                                                 unsigned short* __restrict__ out) {
  int row = blockIdx.x, tid = threadIdx.x;
  const float* xr = x + (size_t)row * DM;
  float4 a = *(const float4*)&xr[tid * 8];
  float4 b = *(const float4*)&xr[tid * 8 + 4];
  float ss = a.x * a.x + a.y * a.y + a.z * a.z + a.w * a.w +
             b.x * b.x + b.y * b.y + b.z * b.z + b.w * b.w;
#pragma unroll
  for (int off = 32; off > 0; off >>= 1) ss += __shfl_xor(ss, off, 64);
  __shared__ float red[4];
  if ((tid & 63) == 0) red[tid >> 6] = ss;
  __syncthreads();
  float rs = rsqrtf((red[0] + red[1] + red[2] + red[3]) * (1.0f / DM) + 1e-5f);
  float4 ga = *(const float4*)&g[tid * 8];
  float4 gb = *(const float4*)&g[tid * 8 + 4];
  u16x8 o;
  o[0] = f2bf(a.x * rs * ga.x); o[1] = f2bf(a.y * rs * ga.y);
  o[2] = f2bf(a.z * rs * ga.z); o[3] = f2bf(a.w * rs * ga.w);
  o[4] = f2bf(b.x * rs * gb.x); o[5] = f2bf(b.y * rs * gb.y);
  o[6] = f2bf(b.z * rs * gb.z); o[7] = f2bf(b.w * rs * gb.w);
  *(u16x8*)&out[(size_t)row * DM + tid * 8] = o;
}

// ---------------- RoPE in-place on qkv buffer (q cols 0..2047, k cols 2048..3071) ----
__global__ __launch_bounds__(256) void k_rope(unsigned short* __restrict__ qkv,
                                              const float* __restrict__ cosT,
                                              const float* __restrict__ sinT) {
  int idx = blockIdx.x * 256 + threadIdx.x;   // TOK*24*64 total
  int j = idx & 63;
  int hh = (idx >> 6) % 24;
  int tok = idx / (64 * 24);
  int s = tok & (SEQ - 1);
  int colbase = (hh < 16) ? hh * HD : DM + (hh - 16) * HD;
  unsigned short* p = qkv + (size_t)tok * 4096 + colbase;
  float lo = bf2f(p[j]), hi = bf2f(p[j + 64]);
  const float* cr = cosT + (size_t)s * HD;
  const float* sr = sinT + (size_t)s * HD;
  float nl = lo * cr[j] - hi * sr[j];
  float nh = hi * cr[j + 64] + lo * sr[j + 64];
  if (hh < 16) { nl *= QK_SCALE; nh *= QK_SCALE; }   // fold 1/sqrt(HD) into q
  p[j] = f2bf(nl);
  p[j + 64] = f2bf(nh);
}

// ---------------- GEMM: C[M,N] = A[M,K] * Bt[N,K]^T (both bf16 row-major) ----------
// m97 structure: 128x128 tile, BK=32, 4 waves (2x2), global_load_lds width-16.
// EPI 0: store bf16. EPI 1: outF = res + acc (f32), res/outF may alias elementwise.
template <int EPI>
__global__ __launch_bounds__(256) void k_gemm_bt(const unsigned short* __restrict__ A,
                                                 const unsigned short* __restrict__ Bt,
                                                 unsigned short* __restrict__ outB,
                                                 float* outF, const float* res,
                                                 int M, int N, int K) {
  __shared__ __attribute__((aligned(16))) unsigned short lA[128 * 32];
  __shared__ __attribute__((aligned(16))) unsigned short lB[128 * 32];
  int tid = threadIdx.x, w = tid >> 6, l = tid & 63;
  int wr = w >> 1, wc = w & 1, lr = l & 15, lg = l >> 4;
  int m0 = blockIdx.y * 128, n0 = blockIdx.x * 128;
  const unsigned short* Ab = A + (size_t)m0 * K;
  const unsigned short* Bb = Bt + (size_t)n0 * K;
  f32x4 acc[4][4] = {};
  for (int k0 = 0; k0 < K; k0 += 32) {
    __syncthreads();
#pragma unroll
    for (int i = 0; i < 2; i++) {
      int c = i * 256 + tid;                       // 512 16B chunks per tile
      GLDS16(&Ab[(size_t)(c >> 2) * K + k0 + (c & 3) * 8], &lA[(i * 256 + w * 64) * 8]);
      GLDS16(&Bb[(size_t)(c >> 2) * K + k0 + (c & 3) * 8], &lB[(i * 256 + w * 64) * 8]);
    }
    __syncthreads();
    bf16x8 af[4], bfr[4];
#pragma unroll
    for (int m = 0; m < 4; m++)
      af[m] = *(const bf16x8*)&lA[(wr * 64 + m * 16 + lr) * 32 + lg * 8];
#pragma unroll
    for (int n = 0; n < 4; n++)
      bfr[n] = *(const bf16x8*)&lB[(wc * 64 + n * 16 + lr) * 32 + lg * 8];
#pragma unroll
    for (int m = 0; m < 4; m++)
#pragma unroll
      for (int n = 0; n < 4; n++)
        acc[m][n] = __builtin_amdgcn_mfma_f32_16x16x32_bf16(af[m], bfr[n], acc[m][n], 0, 0, 0);
  }
#pragma unroll
  for (int m = 0; m < 4; m++)
#pragma unroll
    for (int n = 0; n < 4; n++)
#pragma unroll
      for (int j = 0; j < 4; j++) {
        size_t row = m0 + wr * 64 + m * 16 + lg * 4 + j;
        size_t col = n0 + wc * 64 + n * 16 + lr;
        if (EPI == 0)
          outB[row * N + col] = f2bf(acc[m][n][j]);
        else
          outF[row * N + col] = res[row * N + col] + acc[m][n][j];
      }
}

// ---------------- fused gate/up GEMM + SwiGLU epilogue --------------------------------
// act[M,FF] = silu(A*Wg^T) * (A*Wu^T), tile 128x64 (per matrix), 4 waves (2x2).
__global__ __launch_bounds__(256) void k_gemm_gateup(const unsigned short* __restrict__ A,
                                                     const unsigned short* __restrict__ Bg,
                                                     const unsigned short* __restrict__ Bu,
                                                     unsigned short* __restrict__ act, int K) {
  __shared__ __attribute__((aligned(16))) unsigned short lA[128 * 32];
  __shared__ __attribute__((aligned(16))) unsigned short lG[64 * 32];
  __shared__ __attribute__((aligned(16))) unsigned short lU[64 * 32];
  int tid = threadIdx.x, w = tid >> 6, l = tid & 63;
  int wr = w >> 1, wc = w & 1, lr = l & 15, lg = l >> 4;
  int m0 = blockIdx.y * 128, n0 = blockIdx.x * 64;
  const unsigned short* Ab = A + (size_t)m0 * K;
  const unsigned short* Gb = Bg + (size_t)n0 * K;
  const unsigned short* Ub = Bu + (size_t)n0 * K;
  f32x4 ag[4][2] = {}, au[4][2] = {};
  for (int k0 = 0; k0 < K; k0 += 32) {
    __syncthreads();
#pragma unroll
    for (int i = 0; i < 2; i++) {
      int c = i * 256 + tid;
      GLDS16(&Ab[(size_t)(c >> 2) * K + k0 + (c & 3) * 8], &lA[(i * 256 + w * 64) * 8]);
    }
    {
      int c = tid;  // 256 chunks each for G/U
      GLDS16(&Gb[(size_t)(c >> 2) * K + k0 + (c & 3) * 8], &lG[(w * 64) * 8]);
      GLDS16(&Ub[(size_t)(c >> 2) * K + k0 + (c & 3) * 8], &lU[(w * 64) * 8]);
    }
    __syncthreads();
    bf16x8 af[4], bg[2], bu[2];
#pragma unroll
    for (int m = 0; m < 4; m++)
      af[m] = *(const bf16x8*)&lA[(wr * 64 + m * 16 + lr) * 32 + lg * 8];
#pragma unroll
    for (int n = 0; n < 2; n++) {
      bg[n] = *(const bf16x8*)&lG[(wc * 32 + n * 16 + lr) * 32 + lg * 8];
      bu[n] = *(const bf16x8*)&lU[(wc * 32 + n * 16 + lr) * 32 + lg * 8];
    }
#pragma unroll
    for (int m = 0; m < 4; m++)
#pragma unroll
      for (int n = 0; n < 2; n++) {
        ag[m][n] = __builtin_amdgcn_mfma_f32_16x16x32_bf16(af[m], bg[n], ag[m][n], 0, 0, 0);
        au[m][n] = __builtin_amdgcn_mfma_f32_16x16x32_bf16(af[m], bu[n], au[m][n], 0, 0, 0);
      }
  }
#pragma unroll
  for (int m = 0; m < 4; m++)
#pragma unroll
    for (int n = 0; n < 2; n++)
#pragma unroll
      for (int j = 0; j < 4; j++) {
        size_t row = m0 + wr * 64 + m * 16 + lg * 4 + j;
        size_t col = n0 + wc * 32 + n * 16 + lr;
        float gv = ag[m][n][j], uv = au[m][n][j];
        float sv = gv / (1.0f + __expf(-gv));
        act[row * FF_ + col] = f2bf(sv * uv);
      }
}

// ---------------- causal GQA flash attention ------------------------------------------
// Block: 64 q rows (4 waves x 16), KV steps of 32. qkv: [tok,4096] = [q 16*128 | k 8*128 | v 8*128].
// Q pre-scaled by 1/sqrt(HD) in k_rope. K tile LDS XOR-swizzled (16B granule ^ (row&7)),
// V staged transposed [128d][32kv] with granule ^ (((row>>2)^row)&3).
__global__ __launch_bounds__(256) void k_attn(const unsigned short* __restrict__ qkv,
                                              unsigned short* __restrict__ out) {
  __shared__ __attribute__((aligned(16))) unsigned short lK[32 * 128];
  __shared__ __attribute__((aligned(16))) unsigned short lV[128 * 32];
  __shared__ __attribute__((aligned(16))) unsigned short lP[4 * 16 * 32];
  int q0 = blockIdx.x * 64;
  int h = blockIdx.y;
  int b = blockIdx.z;
  int tid = threadIdx.x, w = tid >> 6, l = tid & 63;
  int lr = l & 15, lg = l >> 4;
  const unsigned short* base = qkv + (size_t)b * SEQ * 4096;
  const unsigned short* Qp = base + (size_t)q0 * 4096 + h * HD;
  const unsigned short* Kp = base + 2048 + (h >> 1) * HD;
  const unsigned short* Vp = base + 3072 + (h >> 1) * HD;

  bf16x8 qf[4];
#pragma unroll
  for (int d = 0; d < 4; d++)
    qf[d] = *(const bf16x8*)&Qp[(size_t)(w * 16 + lr) * 4096 + d * 32 + lg * 8];

  f32x4 oacc[8] = {};
  float mrow[4];
  float lsum[4] = {0.f, 0.f, 0.f, 0.f};
#pragma unroll
  for (int j = 0; j < 4; j++) mrow[j] = -__builtin_inff();

  int vkvp = tid & 15, vdc = tid >> 4;

  for (int kv0 = 0; kv0 < q0 + 64; kv0 += 32) {
    __syncthreads();
    // K tile (32 rows x 128 cols), swizzled source so linear-LDS == swizzled layout
#pragma unroll
    for (int i = 0; i < 2; i++) {
      int c = i * 256 + tid;
      int krow = c >> 4, cc = c & 15;
      GLDS16(&Kp[(size_t)(kv0 + krow) * 4096 + ((cc ^ (krow & 7)) * 8)],
             &lK[(i * 256 + w * 64) * 8]);
    }
    // V tile transposed via registers: [128 d][32 kv], pack 2 kv per u32 write
    {
      const unsigned short* vp = &Vp[(size_t)(kv0 + 2 * vkvp) * 4096 + vdc * 8];
      u16x8 v0 = *(const u16x8*)vp;
      u16x8 v1 = *(const u16x8*)(vp + 4096);
#pragma unroll
      for (int j = 0; j < 8; j++) {
        int row = vdc * 8 + j;
        int sw = ((row >> 2) ^ row) & 3;
        unsigned int pk = (unsigned int)v0[j] | ((unsigned int)v1[j] << 16);
        *(unsigned int*)&lV[row * 32 + ((vkvp >> 2) ^ sw) * 8 + (vkvp & 3) * 2] = pk;
      }
    }
    __syncthreads();

    // scores: S^[16q x 32kv] per wave; mfma(Q, K^T)
    f32x4 sa[2] = {};
#pragma unroll
    for (int kh = 0; kh < 2; kh++) {
      int krow = kh * 16 + lr;
#pragma unroll
      for (int d = 0; d < 4; d++) {
        bf16x8 kf = *(const bf16x8*)&lK[krow * 128 + (((d * 4 + lg) ^ (lr & 7)) * 8)];
        sa[kh] = __builtin_amdgcn_mfma_f32_16x16x32_bf16(qf[d], kf, sa[kh], 0, 0, 0);
      }
    }
    // causal mask (only when this wave's rows can be exceeded)
    if (kv0 + 31 > q0 + w * 16) {
#pragma unroll
      for (int kh = 0; kh < 2; kh++)
#pragma unroll
        for (int j = 0; j < 4; j++) {
          int col = kv0 + kh * 16 + lr;
          int row = q0 + w * 16 + lg * 4 + j;
          if (col > row) sa[kh][j] = -__builtin_inff();
        }
    }
    // online softmax (rows live across 16-lane groups; reduce over l&15)
    float mx[4], fct[4], ps[4];
#pragma unroll
    for (int j = 0; j < 4; j++) mx[j] = fmaxf(sa[0][j], sa[1][j]);
#pragma unroll
    for (int off = 8; off > 0; off >>= 1)
#pragma unroll
      for (int j = 0; j < 4; j++) mx[j] = fmaxf(mx[j], __shfl_xor(mx[j], off, 64));
#pragma unroll
    for (int j = 0; j < 4; j++) {
      float nm = fmaxf(mrow[j], mx[j]);
      fct[j] = __expf(mrow[j] - nm);
      mrow[j] = nm;
    }
#pragma unroll
    for (int kh = 0; kh < 2; kh++)
#pragma unroll
      for (int j = 0; j < 4; j++) sa[kh][j] = __expf(sa[kh][j] - mrow[j]);
#pragma unroll
    for (int j = 0; j < 4; j++) ps[j] = sa[0][j] + sa[1][j];
#pragma unroll
    for (int off = 8; off > 0; off >>= 1)
#pragma unroll
      for (int j = 0; j < 4; j++) ps[j] += __shfl_xor(ps[j], off, 64);
#pragma unroll
    for (int j = 0; j < 4; j++) lsum[j] = lsum[j] * fct[j] + ps[j];
#pragma unroll
    for (int c = 0; c < 8; c++)
#pragma unroll
      for (int j = 0; j < 4; j++) oacc[c][j] *= fct[j];
    // P -> per-wave LDS [16q][32kv] (bf16), then read back as A-fragment
#pragma unroll
    for (int kh = 0; kh < 2; kh++)
#pragma unroll
      for (int j = 0; j < 4; j++)
        lP[(w * 16 + lg * 4 + j) * 32 + kh * 16 + lr] = f2bf(sa[kh][j]);
    asm volatile("" ::: "memory");  // order P stores before the vector reload
    bf16x8 pf = *(const bf16x8*)&lP[(w * 16 + lr) * 32 + lg * 8];
    // PV: O[16q x 128d] += P[16x32] * V[32x128]
#pragma unroll
    for (int c = 0; c < 8; c++) {
      int vrow = c * 16 + lr;
      int sw = ((vrow >> 2) ^ vrow) & 3;
      bf16x8 vf = *(const bf16x8*)&lV[vrow * 32 + ((lg ^ sw) * 8)];
      oacc[c] = __builtin_amdgcn_mfma_f32_16x16x32_bf16(pf, vf, oacc[c], 0, 0, 0);
    }
  }
#pragma unroll
  for (int j = 0; j < 4; j++) {
    float inv = 1.0f / lsum[j];
    int row = q0 + w * 16 + lg * 4 + j;
#pragma unroll
    for (int c = 0; c < 8; c++)
      out[(size_t)(b * SEQ + row) * 2048 + h * HD + c * 16 + lr] = f2bf(oacc[c][j] * inv);
  }
}

// ---------------- launcher -------------------------------------------------------------
extern "C" void kernel_launch(void* const* d_in, const int* in_sizes, int n_in,
                              void* d_out, int out_size, void* d_ws, size_t ws_size,
                              hipStream_t stream) {
  const float* x = (const float*)d_in[0];
  const float* cosT = (const float*)d_in[1];
  const float* sinT = (const float*)d_in[2];
  const float* wq = (const float*)d_in[3];
  const float* wk = (const float*)d_in[4];
  const float* wv = (const float*)d_in[5];
  const float* wo = (const float*)d_in[6];
  const float* wg = (const float*)d_in[7];
  const float* wu = (const float*)d_in[8];
  const float* wd = (const float*)d_in[9];
  const float* g1 = (const float*)d_in[10];
  const float* g2 = (const float*)d_in[11];
  float* out = (float*)d_out;           // also serves as x1 (f32 residual)
  char* ws = (char*)d_ws;

  unsigned short* wqkv = (unsigned short*)(ws + 0);
  unsigned short* hbuf = (unsigned short*)(ws + 16777216);
  unsigned short* qkv = (unsigned short*)(ws + 33554432);
  unsigned short* attn_o = (unsigned short*)(ws + 67108864);
  unsigned short* wo_bf = (unsigned short*)(ws + 83886080);
  unsigned short* wgu = (unsigned short*)(ws + 33554432);
  unsigned short* act = (unsigned short*)(ws + 92274688);
  unsigned short* wdown = (unsigned short*)(ws + 0);

  // ---- attention sub-block ----
  k_conv<<<2048, 256, 0, stream>>>(wq, wqkv);
  k_conv<<<1024, 256, 0, stream>>>(wk, wqkv + 4194304);
  k_conv<<<1024, 256, 0, stream>>>(wv, wqkv + 6291456);
  k_rmsnorm<<<4096, 256, 0, stream>>>(x, g1, hbuf);
  k_gemm_bt<0><<<dim3(32, 32), 256, 0, stream>>>(hbuf, wqkv, qkv, nullptr, nullptr,
                                                 4096, 4096, 2048);
  k_rope<<<24576, 256, 0, stream>>>(qkv, cosT, sinT);
  k_attn<<<dim3(32, 16, 2), 256, 0, stream>>>(qkv, attn_o);
  k_conv<<<2048, 256, 0, stream>>>(wo, wo_bf);
  k_gemm_bt<1><<<dim3(16, 32), 256, 0, stream>>>(attn_o, wo_bf, nullptr, out, x,
                                                 4096, 2048, 2048);
  // ---- SwiGLU MLP sub-block ----
  k_rmsnorm<<<4096, 256, 0, stream>>>(out, g2, hbuf);
  k_conv<<<5504, 256, 0, stream>>>(wg, wgu);
  k_conv<<<5504, 256, 0, stream>>>(wu, wgu + 11272192);
  k_gemm_gateup<<<dim3(86, 32), 256, 0, stream>>>(hbuf, wgu, wgu + 11272192, act, 2048);
  k_conv<<<5504, 256, 0, stream>>>(wd, wdown);
  k_gemm_bt<1><<<dim3(16, 32), 256, 0, stream>>>(act, wdown, nullptr, out, out,
                                                 4096, 2048, 5504);
}

// Round 2
// 768.639 us; speedup vs baseline: 1.1692x; 1.1692x over previous
//
#include <hip/hip_runtime.h>

// LLM block: B=2,S=2048,D=2048,H=16,KVH=8,HD=128,FF=5504, f32 in/out, bf16 MFMA compute.
// Workspace layout (bytes), peak ~137MB:
//   wqkv_bf16   [4096,2048]  @ 0
//   h/h2_bf16   [4096,2048]  @ 16777216
//   qkv_bf16    [4096,4096]  @ 33554432   (region reused later by wgu)
//   attn_out    [4096,2048]  @ 67108864
//   wo_bf16     [2048,2048]  @ 83886080
//   wgu_bf16    [11008,2048] @ 33554432   (interleaved: per 256-row group = 128 gate | 128 up)
//   act_bf16    [4096,5504]  @ 92274688
//   wdown_bf16  [2048,5504]  @ 0
//   x1 (f32 residual) lives in d_out.

#define DM 2048
#define SEQ 2048
#define HD 128
#define FF_ 5504
#define QK_SCALE 0.08838834764831845f

typedef __bf16 bf16x8 __attribute__((ext_vector_type(8)));
typedef float f32x4 __attribute__((ext_vector_type(4)));
typedef unsigned short u16x8 __attribute__((ext_vector_type(8)));

typedef __attribute__((address_space(1))) void* gas1;
typedef __attribute__((address_space(3))) void* las3;
#define GLDS16(g, s) __builtin_amdgcn_global_load_lds((gas1)(g), (las3)(s), 16, 0, 0)

static __device__ __forceinline__ float bf2f(unsigned short u) {
  union { unsigned int i; float f; } c; c.i = ((unsigned int)u) << 16; return c.f;
}
static __device__ __forceinline__ unsigned short f2bf(float f) {
  __bf16 b = (__bf16)f;
  return __builtin_bit_cast(unsigned short, b);
}

// ---------------- f32 -> bf16 convert (8 elems/thread, exact grid) ----------------
__global__ __launch_bounds__(256) void k_conv(const float* __restrict__ src,
                                              unsigned short* __restrict__ dst) {
  size_t i = (size_t)(blockIdx.x * 256 + threadIdx.x) * 8;
  float4 a = *(const float4*)&src[i];
  float4 b = *(const float4*)&src[i + 4];
  u16x8 o;
  o[0] = f2bf(a.x); o[1] = f2bf(a.y); o[2] = f2bf(a.z); o[3] = f2bf(a.w);
  o[4] = f2bf(b.x); o[5] = f2bf(b.y); o[6] = f2bf(b.z); o[7] = f2bf(b.w);
  *(u16x8*)&dst[i] = o;
}

// ---- gate/up interleaved convert: dst row r of group t: r<128 -> wg, else wu ----
__global__ __launch_bounds__(256) void k_conv_gu(const float* __restrict__ g,
                                                 const float* __restrict__ u,
                                                 unsigned short* __restrict__ dst) {
  int i = blockIdx.x * 256 + threadIdx.x;   // one per 8 elems; 11008*256 threads
  int row = i >> 8;
  int c8 = (i & 255) * 8;
  int t = row >> 8, r = row & 255;
  const float* src = (r < 128) ? (g + (size_t)(t * 128 + r) * DM + c8)
                               : (u + (size_t)(t * 128 + (r - 128)) * DM + c8);
  float4 a = *(const float4*)src;
  float4 b = *(const float4*)(src + 4);
  u16x8 o;
  o[0] = f2bf(a.x); o[1] = f2bf(a.y); o[2] = f2bf(a.z); o[3] = f2bf(a.w);
  o[4] = f2bf(b.x); o[5] = f2bf(b.y); o[6] = f2bf(b.z); o[7] = f2bf(b.w);
  *(u16x8*)&dst[(size_t)row * DM + c8] = o;
}

// ---------------- RMSNorm: one block per row (D=2048, 8 f32/thread) ----------------
__global__ __launch_bounds__(256) void k_rmsnorm(const float* __restrict__ x,
                                                 const float* __restrict__ g,
                                                 unsigned short* __restrict__ out) {
  int row = blockIdx.x, tid = threadIdx.x;
  const float* xr = x + (size_t)row * DM;
  float4 a = *(const float4*)&xr[tid * 8];
  float4 b = *(const float4*)&xr[tid * 8 + 4];
  float ss = a.x * a.x + a.y * a.y + a.z * a.z + a.w * a.w +
             b.x * b.x + b.y * b.y + b.z * b.z + b.w * b.w;
#pragma unroll
  for (int off = 32; off > 0; off >>= 1) ss += __shfl_xor(ss, off, 64);
  __shared__ float red[4];
  if ((tid & 63) == 0) red[tid >> 6] = ss;
  __syncthreads();
  float rs = rsqrtf((red[0] + red[1] + red[2] + red[3]) * (1.0f / DM) + 1e-5f);
  float4 ga = *(const float4*)&g[tid * 8];
  float4 gb = *(const float4*)&g[tid * 8 + 4];
  u16x8 o;
  o[0] = f2bf(a.x * rs * ga.x); o[1] = f2bf(a.y * rs * ga.y);
  o[2] = f2bf(a.z * rs * ga.z); o[3] = f2bf(a.w * rs * ga.w);
  o[4] = f2bf(b.x * rs * gb.x); o[5] = f2bf(b.y * rs * gb.y);
  o[6] = f2bf(b.z * rs * gb.z); o[7] = f2bf(b.w * rs * gb.w);
  *(u16x8*)&out[(size_t)row * DM + tid * 8] = o;
}

// ---------------- RoPE in-place on qkv buffer (q cols 0..2047, k cols 2048..3071) ----
__global__ __launch_bounds__(256) void k_rope(unsigned short* __restrict__ qkv,
                                              const float* __restrict__ cosT,
                                              const float* __restrict__ sinT) {
  int idx = blockIdx.x * 256 + threadIdx.x;   // TOK*24*64 total
  int j = idx & 63;
  int hh = (idx >> 6) % 24;
  int tok = idx / (64 * 24);
  int s = tok & (SEQ - 1);
  int colbase = (hh < 16) ? hh * HD : DM + (hh - 16) * HD;
  unsigned short* p = qkv + (size_t)tok * 4096 + colbase;
  float lo = bf2f(p[j]), hi = bf2f(p[j + 64]);
  const float* cr = cosT + (size_t)s * HD;
  const float* sr = sinT + (size_t)s * HD;
  float nl = lo * cr[j] - hi * sr[j];
  float nh = hi * cr[j + 64] + lo * sr[j + 64];
  if (hh < 16) { nl *= QK_SCALE; nh *= QK_SCALE; }   // fold 1/sqrt(HD) into q
  p[j] = f2bf(nl);
  p[j + 64] = f2bf(nh);
}

// ---------------- deep-pipelined GEMM: C[M,N] = A[M,K] * Bt[N,K]^T --------------------
// BM=256, BK=32, 8 waves (2Mx4N), 4 LDS buffers, counted vmcnt, setprio, XOR swizzle.
// BN=256: 2 phases/K-tile (16 MFMA each). BN=128: 1 phase/K-tile (16 MFMA).
// Stage of K-tile t+3 -> buf[(t+3)&3] overlaps compute of buf[t&3] (always distinct).
// Swizzle: LDS 16B-granule g' = g ^ (row&3); source pre-swizzled, reads swizzled.
// EPI 0: store bf16. EPI 1: outF = res + acc. EPI 2: gateup silu via LDS (act [M,5504]).
template <int BN, int EPI>
__global__ __launch_bounds__(512, 2) void k_gemm8(
    const unsigned short* __restrict__ A, const unsigned short* __restrict__ Bt,
    unsigned short* __restrict__ outB, float* __restrict__ outF,
    const float* __restrict__ res, int N, int K) {
  constexpr int NF = BN / 64;            // n-frags per wave: 4 or 2
  constexpr int BSTMT = BN / 128;        // B stage stmts: 2 or 1
  constexpr int ABY = 256 * 64;          // A-tile bytes 16384
  constexpr int BBY = BN * 64;
  constexpr int BUF = ABY + BBY;
  constexpr int VPK = 2 + BSTMT;         // vmem instrs / wave / K-tile
  __shared__ __attribute__((aligned(16))) unsigned char smem[4 * BUF];

  const int tid = threadIdx.x, w = tid >> 6, l = tid & 63;
  const int wr = w >> 2, wc = w & 3, lr = l & 15, lg = l >> 4;
  const int nwg = gridDim.x, bid = blockIdx.x;
  const int bswz = (bid & 7) * (nwg >> 3) + (bid >> 3);   // XCD swizzle (nwg%8==0)
  const int mt = bswz & 15, nt = bswz >> 4;               // MT=16 fixed (M=4096)
  const int m0 = mt * 256, n0 = nt * BN;
  const int nk = K >> 5;

  const int srow = w * 16 + (l >> 2);
  const int sg8 = ((l & 3) ^ ((l >> 2) & 3)) * 8;         // pre-swizzled source granule
  const unsigned short* Asrc = A + (size_t)(m0 + srow) * K + sg8;
  const unsigned short* Bsrc = Bt + (size_t)(n0 + srow) * K + sg8;
  const int aoff = (wr * 128 + lr) * 64 + ((lg ^ (lr & 3)) << 4);
  const int boff = (wc * (BN / 4) + lr) * 64 + ((lg ^ (lr & 3)) << 4);

  auto stageA = [&](int kt) {
    unsigned char* bb = smem + (kt & 3) * BUF;
#pragma unroll
    for (int i = 0; i < 2; i++)
      GLDS16(Asrc + (size_t)i * 128 * K + kt * 32, bb + (i * 512 + w * 64) * 16);
  };
  auto stageB = [&](int kt) {
    unsigned char* bb = smem + (kt & 3) * BUF + ABY;
#pragma unroll
    for (int i = 0; i < BSTMT; i++)
      GLDS16(Bsrc + (size_t)i * 128 * K + kt * 32, bb + (i * 512 + w * 64) * 16);
  };

  f32x4 acc[8][NF] = {};

  // prologue: stage K0..K2, wait K0, publish
  for (int kt = 0; kt < 3; kt++) { stageA(kt); stageB(kt); }
  asm volatile("s_waitcnt vmcnt(%0)" ::"i"(2 * VPK) : "memory");
  __builtin_amdgcn_s_barrier();

  for (int kt = 0; kt < nk; kt++) {
    unsigned char* ba = smem + (kt & 3) * BUF;
    unsigned char* bb = ba + ABY;
    const bool st = (kt + 3) < nk;
    if constexpr (BN == 256) {
      bf16x8 am[4], bnf[4];
#pragma unroll
      for (int m = 0; m < 4; m++) am[m] = *(const bf16x8*)(ba + aoff + m * 1024);
#pragma unroll
      for (int n = 0; n < 4; n++) bnf[n] = *(const bf16x8*)(bb + boff + n * 1024);
      if (st) stageA(kt + 3);
      __builtin_amdgcn_s_barrier();
      __builtin_amdgcn_s_setprio(1);
#pragma unroll
      for (int m = 0; m < 4; m++)
#pragma unroll
        for (int n = 0; n < 4; n++)
          acc[m][n] = __builtin_amdgcn_mfma_f32_16x16x32_bf16(am[m], bnf[n], acc[m][n], 0, 0, 0);
      __builtin_amdgcn_s_setprio(0);
      __builtin_amdgcn_s_barrier();
#pragma unroll
      for (int m = 0; m < 4; m++) am[m] = *(const bf16x8*)(ba + aoff + (m + 4) * 1024);
      if (st) stageB(kt + 3);
      __builtin_amdgcn_s_barrier();
      __builtin_amdgcn_s_setprio(1);
#pragma unroll
      for (int m = 0; m < 4; m++)
#pragma unroll
        for (int n = 0; n < 4; n++)
          acc[m + 4][n] = __builtin_amdgcn_mfma_f32_16x16x32_bf16(am[m], bnf[n], acc[m + 4][n], 0, 0, 0);
      __builtin_amdgcn_s_setprio(0);
      if (kt <= nk - 4)      asm volatile("s_waitcnt vmcnt(%0)" ::"i"(2 * VPK) : "memory");
      else if (kt == nk - 3) asm volatile("s_waitcnt vmcnt(%0)" ::"i"(VPK) : "memory");
      else if (kt == nk - 2) asm volatile("s_waitcnt vmcnt(0)" ::: "memory");
      __builtin_amdgcn_s_barrier();
    } else {
      bf16x8 am[8], bnf[2];
#pragma unroll
      for (int m = 0; m < 8; m++) am[m] = *(const bf16x8*)(ba + aoff + m * 1024);
#pragma unroll
      for (int n = 0; n < 2; n++) bnf[n] = *(const bf16x8*)(bb + boff + n * 1024);
      if (st) { stageA(kt + 3); stageB(kt + 3); }
      __builtin_amdgcn_s_barrier();
      __builtin_amdgcn_s_setprio(1);
#pragma unroll
      for (int m = 0; m < 8; m++)
#pragma unroll
        for (int n = 0; n < 2; n++)
          acc[m][n] = __builtin_amdgcn_mfma_f32_16x16x32_bf16(am[m], bnf[n], acc[m][n], 0, 0, 0);
      __builtin_amdgcn_s_setprio(0);
      if (kt <= nk - 4)      asm volatile("s_waitcnt vmcnt(%0)" ::"i"(2 * VPK) : "memory");
      else if (kt == nk - 3) asm volatile("s_waitcnt vmcnt(%0)" ::"i"(VPK) : "memory");
      else if (kt == nk - 2) asm volatile("s_waitcnt vmcnt(0)" ::: "memory");
      __builtin_amdgcn_s_barrier();
    }
  }

  const int rbase = wr * 128 + lg * 4;
  const int cbase = wc * (BN / 4) + lr;
  if constexpr (EPI == 0) {
#pragma unroll
    for (int m = 0; m < 8; m++)
#pragma unroll
      for (int n = 0; n < NF; n++)
#pragma unroll
        for (int j = 0; j < 4; j++)
          outB[(size_t)(m0 + rbase + m * 16 + j) * N + n0 + cbase + n * 16] =
              f2bf(acc[m][n][j]);
  } else if constexpr (EPI == 1) {
#pragma unroll
    for (int m = 0; m < 8; m++)
#pragma unroll
      for (int n = 0; n < NF; n++)
#pragma unroll
        for (int j = 0; j < 4; j++) {
          size_t o = (size_t)(m0 + rbase + m * 16 + j) * N + n0 + cbase + n * 16;
          outF[o] = res[o] + acc[m][n][j];
        }
  } else {
    // gateup: waves wc<2 hold gate (block cols 0..127), wc>=2 hold up (128..255).
    float* gl = (float*)smem;   // [256][128] f32 = 128 KiB (reuse staging LDS)
    if (wc < 2) {
#pragma unroll
      for (int m = 0; m < 8; m++)
#pragma unroll
        for (int n = 0; n < NF; n++)
#pragma unroll
          for (int j = 0; j < 4; j++)
            gl[(rbase + m * 16 + j) * 128 + wc * 64 + n * 16 + lr] = acc[m][n][j];
    }
    __syncthreads();
    if (wc >= 2) {
      const int ab = n0 >> 1;   // act col base (128 ff-cols per block)
#pragma unroll
      for (int m = 0; m < 8; m++)
#pragma unroll
        for (int n = 0; n < NF; n++)
#pragma unroll
          for (int j = 0; j < 4; j++) {
            int rl = rbase + m * 16 + j;
            int cl = (wc - 2) * 64 + n * 16 + lr;
            float g = gl[rl * 128 + cl];
            float s = g / (1.0f + __expf(-g));
            outB[(size_t)(m0 + rl) * FF_ + ab + cl] = f2bf(s * acc[m][n][j]);
          }
    }
  }
}

// ---------------- causal GQA flash attention (unchanged from r1) ----------------------
__global__ __launch_bounds__(256) void k_attn(const unsigned short* __restrict__ qkv,
                                              unsigned short* __restrict__ out) {
  __shared__ __attribute__((aligned(16))) unsigned short lK[32 * 128];
  __shared__ __attribute__((aligned(16))) unsigned short lV[128 * 32];
  __shared__ __attribute__((aligned(16))) unsigned short lP[4 * 16 * 32];
  int q0 = blockIdx.x * 64;
  int h = blockIdx.y;
  int b = blockIdx.z;
  int tid = threadIdx.x, w = tid >> 6, l = tid & 63;
  int lr = l & 15, lg = l >> 4;
  const unsigned short* base = qkv + (size_t)b * SEQ * 4096;
  const unsigned short* Qp = base + (size_t)q0 * 4096 + h * HD;
  const unsigned short* Kp = base + 2048 + (h >> 1) * HD;
  const unsigned short* Vp = base + 3072 + (h >> 1) * HD;

  bf16x8 qf[4];
#pragma unroll
  for (int d = 0; d < 4; d++)
    qf[d] = *(const bf16x8*)&Qp[(size_t)(w * 16 + lr) * 4096 + d * 32 + lg * 8];

  f32x4 oacc[8] = {};
  float mrow[4];
  float lsum[4] = {0.f, 0.f, 0.f, 0.f};
#pragma unroll
  for (int j = 0; j < 4; j++) mrow[j] = -__builtin_inff();

  int vkvp = tid & 15, vdc = tid >> 4;

  for (int kv0 = 0; kv0 < q0 + 64; kv0 += 32) {
    __syncthreads();
#pragma unroll
    for (int i = 0; i < 2; i++) {
      int c = i * 256 + tid;
      int krow = c >> 4, cc = c & 15;
      GLDS16(&Kp[(size_t)(kv0 + krow) * 4096 + ((cc ^ (krow & 7)) * 8)],
             &lK[(i * 256 + w * 64) * 8]);
    }
    {
      const unsigned short* vp = &Vp[(size_t)(kv0 + 2 * vkvp) * 4096 + vdc * 8];
      u16x8 v0 = *(const u16x8*)vp;
      u16x8 v1 = *(const u16x8*)(vp + 4096);
#pragma unroll
      for (int j = 0; j < 8; j++) {
        int row = vdc * 8 + j;
        int sw = ((row >> 2) ^ row) & 3;
        unsigned int pk = (unsigned int)v0[j] | ((unsigned int)v1[j] << 16);
        *(unsigned int*)&lV[row * 32 + ((vkvp >> 2) ^ sw) * 8 + (vkvp & 3) * 2] = pk;
      }
    }
    __syncthreads();

    f32x4 sa[2] = {};
#pragma unroll
    for (int kh = 0; kh < 2; kh++) {
      int krow = kh * 16 + lr;
#pragma unroll
      for (int d = 0; d < 4; d++) {
        bf16x8 kf = *(const bf16x8*)&lK[krow * 128 + (((d * 4 + lg) ^ (lr & 7)) * 8)];
        sa[kh] = __builtin_amdgcn_mfma_f32_16x16x32_bf16(qf[d], kf, sa[kh], 0, 0, 0);
      }
    }
    if (kv0 + 31 > q0 + w * 16) {
#pragma unroll
      for (int kh = 0; kh < 2; kh++)
#pragma unroll
        for (int j = 0; j < 4; j++) {
          int col = kv0 + kh * 16 + lr;
          int row = q0 + w * 16 + lg * 4 + j;
          if (col > row) sa[kh][j] = -__builtin_inff();
        }
    }
    float mx[4], fct[4], ps[4];
#pragma unroll
    for (int j = 0; j < 4; j++) mx[j] = fmaxf(sa[0][j], sa[1][j]);
#pragma unroll
    for (int off = 8; off > 0; off >>= 1)
#pragma unroll
      for (int j = 0; j < 4; j++) mx[j] = fmaxf(mx[j], __shfl_xor(mx[j], off, 64));
#pragma unroll
    for (int j = 0; j < 4; j++) {
      float nm = fmaxf(mrow[j], mx[j]);
      fct[j] = __expf(mrow[j] - nm);
      mrow[j] = nm;
    }
#pragma unroll
    for (int kh = 0; kh < 2; kh++)
#pragma unroll
      for (int j = 0; j < 4; j++) sa[kh][j] = __expf(sa[kh][j] - mrow[j]);
#pragma unroll
    for (int j = 0; j < 4; j++) ps[j] = sa[0][j] + sa[1][j];
#pragma unroll
    for (int off = 8; off > 0; off >>= 1)
#pragma unroll
      for (int j = 0; j < 4; j++) ps[j] += __shfl_xor(ps[j], off, 64);
#pragma unroll
    for (int j = 0; j < 4; j++) lsum[j] = lsum[j] * fct[j] + ps[j];
#pragma unroll
    for (int c = 0; c < 8; c++)
#pragma unroll
      for (int j = 0; j < 4; j++) oacc[c][j] *= fct[j];
#pragma unroll
    for (int kh = 0; kh < 2; kh++)
#pragma unroll
      for (int j = 0; j < 4; j++)
        lP[(w * 16 + lg * 4 + j) * 32 + kh * 16 + lr] = f2bf(sa[kh][j]);
    asm volatile("" ::: "memory");
    bf16x8 pf = *(const bf16x8*)&lP[(w * 16 + lr) * 32 + lg * 8];
#pragma unroll
    for (int c = 0; c < 8; c++) {
      int vrow = c * 16 + lr;
      int sw = ((vrow >> 2) ^ vrow) & 3;
      bf16x8 vf = *(const bf16x8*)&lV[vrow * 32 + ((lg ^ sw) * 8)];
      oacc[c] = __builtin_amdgcn_mfma_f32_16x16x32_bf16(pf, vf, oacc[c], 0, 0, 0);
    }
  }
#pragma unroll
  for (int j = 0; j < 4; j++) {
    float inv = 1.0f / lsum[j];
    int row = q0 + w * 16 + lg * 4 + j;
#pragma unroll
    for (int c = 0; c < 8; c++)
      out[(size_t)(b * SEQ + row) * 2048 + h * HD + c * 16 + lr] = f2bf(oacc[c][j] * inv);
  }
}

// ---------------- launcher -------------------------------------------------------------
extern "C" void kernel_launch(void* const* d_in, const int* in_sizes, int n_in,
                              void* d_out, int out_size, void* d_ws, size_t ws_size,
                              hipStream_t stream) {
  const float* x = (const float*)d_in[0];
  const float* cosT = (const float*)d_in[1];
  const float* sinT = (const float*)d_in[2];
  const float* wq = (const float*)d_in[3];
  const float* wk = (const float*)d_in[4];
  const float* wv = (const float*)d_in[5];
  const float* wo = (const float*)d_in[6];
  const float* wg = (const float*)d_in[7];
  const float* wu = (const float*)d_in[8];
  const float* wd = (const float*)d_in[9];
  const float* g1 = (const float*)d_in[10];
  const float* g2 = (const float*)d_in[11];
  float* out = (float*)d_out;           // also serves as x1 (f32 residual)
  char* ws = (char*)d_ws;

  unsigned short* wqkv = (unsigned short*)(ws + 0);
  unsigned short* hbuf = (unsigned short*)(ws + 16777216);
  unsigned short* qkv = (unsigned short*)(ws + 33554432);
  unsigned short* attn_o = (unsigned short*)(ws + 67108864);
  unsigned short* wo_bf = (unsigned short*)(ws + 83886080);
  unsigned short* wgu = (unsigned short*)(ws + 33554432);
  unsigned short* act = (unsigned short*)(ws + 92274688);
  unsigned short* wdown = (unsigned short*)(ws + 0);

  // ---- attention sub-block ----
  k_conv<<<2048, 256, 0, stream>>>(wq, wqkv);
  k_conv<<<1024, 256, 0, stream>>>(wk, wqkv + 4194304);
  k_conv<<<1024, 256, 0, stream>>>(wv, wqkv + 6291456);
  k_rmsnorm<<<4096, 256, 0, stream>>>(x, g1, hbuf);
  k_gemm8<256, 0><<<256, 512, 0, stream>>>(hbuf, wqkv, qkv, nullptr, nullptr,
                                           4096, 2048);
  k_rope<<<24576, 256, 0, stream>>>(qkv, cosT, sinT);
  k_attn<<<dim3(32, 16, 2), 256, 0, stream>>>(qkv, attn_o);
  k_conv<<<2048, 256, 0, stream>>>(wo, wo_bf);
  k_gemm8<128, 1><<<256, 512, 0, stream>>>(attn_o, wo_bf, nullptr, out, x,
                                           2048, 2048);
  // ---- SwiGLU MLP sub-block ----
  k_rmsnorm<<<4096, 256, 0, stream>>>(out, g2, hbuf);
  k_conv_gu<<<11008, 256, 0, stream>>>(wg, wu, wgu);
  k_gemm8<256, 2><<<688, 512, 0, stream>>>(hbuf, wgu, act, nullptr, nullptr,
                                           11008, 2048);
  k_conv<<<5504, 256, 0, stream>>>(wd, wdown);
  k_gemm8<128, 1><<<256, 512, 0, stream>>>(act, wdown, nullptr, out, out,
                                           2048, 5504);
}

// Round 4
// 635.440 us; speedup vs baseline: 1.4143x; 1.2096x over previous
//
#include <hip/hip_runtime.h>

// LLM block: B=2,S=2048,D=2048,H=16,KVH=8,HD=128,FF=5504, f32 in/out, bf16 MFMA compute.
// Workspace layout (bytes), peak ~137MB:
//   wqkv_bf16   [4096,2048]  @ 0
//   h/h2_bf16   [4096,2048]  @ 16777216
//   qkv_bf16    [4096,4096]  @ 33554432   (region reused later by wgu)
//   attn_out    [4096,2048]  @ 67108864
//   wo_bf16     [2048,2048]  @ 83886080
//   wgu_bf16    [11008,2048] @ 33554432   (interleaved: per 256-row group = 128 gate | 128 up)
//   act_bf16    [4096,5504]  @ 92274688
//   wdown_bf16  [2048,5504]  @ 0
//   x1 (f32 residual) lives in d_out.

#define DM 2048
#define SEQ 2048
#define HD 128
#define FF_ 5504
// 1/sqrt(128) * log2(e): attention runs softmax in exp2 domain.
#define QK_SCALE_L2E 0.12751744f

typedef __bf16 bf16x8 __attribute__((ext_vector_type(8)));
typedef float f32x4 __attribute__((ext_vector_type(4)));
typedef float f32x16 __attribute__((ext_vector_type(16)));
typedef unsigned short u16x8 __attribute__((ext_vector_type(8)));
typedef unsigned int u32x4 __attribute__((ext_vector_type(4)));

typedef __attribute__((address_space(1))) void* gas1;
typedef __attribute__((address_space(3))) void* las3;
#define GLDS16(g, s) __builtin_amdgcn_global_load_lds((gas1)(g), (las3)(s), 16, 0, 0)

static __device__ __forceinline__ float bf2f(unsigned short u) {
  union { unsigned int i; float f; } c; c.i = ((unsigned int)u) << 16; return c.f;
}
static __device__ __forceinline__ unsigned short f2bf(float f) {
  __bf16 b = (__bf16)f;
  return __builtin_bit_cast(unsigned short, b);
}
static __device__ __forceinline__ unsigned int pk2(float a, float b) {
  return (unsigned int)f2bf(a) | ((unsigned int)f2bf(b) << 16);
}
// native exp2 (v_exp_f32); __exp2f doesn't exist in HIP headers (r3 compile fail)
static __device__ __forceinline__ float fexp2(float x) { return exp2f(x); }

// ---------------- f32 -> bf16 convert (8 elems/thread, exact grid) ----------------
__global__ __launch_bounds__(256) void k_conv(const float* __restrict__ src,
                                              unsigned short* __restrict__ dst) {
  size_t i = (size_t)(blockIdx.x * 256 + threadIdx.x) * 8;
  float4 a = *(const float4*)&src[i];
  float4 b = *(const float4*)&src[i + 4];
  u16x8 o;
  o[0] = f2bf(a.x); o[1] = f2bf(a.y); o[2] = f2bf(a.z); o[3] = f2bf(a.w);
  o[4] = f2bf(b.x); o[5] = f2bf(b.y); o[6] = f2bf(b.z); o[7] = f2bf(b.w);
  *(u16x8*)&dst[i] = o;
}

// ---- gate/up interleaved convert: dst row r of group t: r<128 -> wg, else wu ----
__global__ __launch_bounds__(256) void k_conv_gu(const float* __restrict__ g,
                                                 const float* __restrict__ u,
                                                 unsigned short* __restrict__ dst) {
  int i = blockIdx.x * 256 + threadIdx.x;
  int row = i >> 8;
  int c8 = (i & 255) * 8;
  int t = row >> 8, r = row & 255;
  const float* src = (r < 128) ? (g + (size_t)(t * 128 + r) * DM + c8)
                               : (u + (size_t)(t * 128 + (r - 128)) * DM + c8);
  float4 a = *(const float4*)src;
  float4 b = *(const float4*)(src + 4);
  u16x8 o;
  o[0] = f2bf(a.x); o[1] = f2bf(a.y); o[2] = f2bf(a.z); o[3] = f2bf(a.w);
  o[4] = f2bf(b.x); o[5] = f2bf(b.y); o[6] = f2bf(b.z); o[7] = f2bf(b.w);
  *(u16x8*)&dst[(size_t)row * DM + c8] = o;
}

// ---------------- RMSNorm: one block per row (D=2048, 8 f32/thread) ----------------
__global__ __launch_bounds__(256) void k_rmsnorm(const float* __restrict__ x,
                                                 const float* __restrict__ g,
                                                 unsigned short* __restrict__ out) {
  int row = blockIdx.x, tid = threadIdx.x;
  const float* xr = x + (size_t)row * DM;
  float4 a = *(const float4*)&xr[tid * 8];
  float4 b = *(const float4*)&xr[tid * 8 + 4];
  float ss = a.x * a.x + a.y * a.y + a.z * a.z + a.w * a.w +
             b.x * b.x + b.y * b.y + b.z * b.z + b.w * b.w;
#pragma unroll
  for (int off = 32; off > 0; off >>= 1) ss += __shfl_xor(ss, off, 64);
  __shared__ float red[4];
  if ((tid & 63) == 0) red[tid >> 6] = ss;
  __syncthreads();
  float rs = rsqrtf((red[0] + red[1] + red[2] + red[3]) * (1.0f / DM) + 1e-5f);
  float4 ga = *(const float4*)&g[tid * 8];
  float4 gb = *(const float4*)&g[tid * 8 + 4];
  u16x8 o;
  o[0] = f2bf(a.x * rs * ga.x); o[1] = f2bf(a.y * rs * ga.y);
  o[2] = f2bf(a.z * rs * ga.z); o[3] = f2bf(a.w * rs * ga.w);
  o[4] = f2bf(b.x * rs * gb.x); o[5] = f2bf(b.y * rs * gb.y);
  o[6] = f2bf(b.z * rs * gb.z); o[7] = f2bf(b.w * rs * gb.w);
  *(u16x8*)&out[(size_t)row * DM + tid * 8] = o;
}

// ---------------- RoPE in-place on qkv buffer (q cols 0..2047, k cols 2048..3071) ----
__global__ __launch_bounds__(256) void k_rope(unsigned short* __restrict__ qkv,
                                              const float* __restrict__ cosT,
                                              const float* __restrict__ sinT) {
  int idx = blockIdx.x * 256 + threadIdx.x;
  int j = idx & 63;
  int hh = (idx >> 6) % 24;
  int tok = idx / (64 * 24);
  int s = tok & (SEQ - 1);
  int colbase = (hh < 16) ? hh * HD : DM + (hh - 16) * HD;
  unsigned short* p = qkv + (size_t)tok * 4096 + colbase;
  float lo = bf2f(p[j]), hi = bf2f(p[j + 64]);
  const float* cr = cosT + (size_t)s * HD;
  const float* sr = sinT + (size_t)s * HD;
  float nl = lo * cr[j] - hi * sr[j];
  float nh = hi * cr[j + 64] + lo * sr[j + 64];
  if (hh < 16) { nl *= QK_SCALE_L2E; nh *= QK_SCALE_L2E; }  // fold scale*log2e into q
  p[j] = f2bf(nl);
  p[j + 64] = f2bf(nh);
}

// ---------------- deep-pipelined GEMM (unchanged from r2) -----------------------------
template <int BN, int EPI>
__global__ __launch_bounds__(512, 2) void k_gemm8(
    const unsigned short* __restrict__ A, const unsigned short* __restrict__ Bt,
    unsigned short* __restrict__ outB, float* __restrict__ outF,
    const float* __restrict__ res, int N, int K) {
  constexpr int NF = BN / 64;
  constexpr int BSTMT = BN / 128;
  constexpr int ABY = 256 * 64;
  constexpr int BBY = BN * 64;
  constexpr int BUF = ABY + BBY;
  constexpr int VPK = 2 + BSTMT;
  __shared__ __attribute__((aligned(16))) unsigned char smem[4 * BUF];

  const int tid = threadIdx.x, w = tid >> 6, l = tid & 63;
  const int wr = w >> 2, wc = w & 3, lr = l & 15, lg = l >> 4;
  const int nwg = gridDim.x, bid = blockIdx.x;
  const int bswz = (bid & 7) * (nwg >> 3) + (bid >> 3);
  const int mt = bswz & 15, nt = bswz >> 4;
  const int m0 = mt * 256, n0 = nt * BN;
  const int nk = K >> 5;

  const int srow = w * 16 + (l >> 2);
  const int sg8 = ((l & 3) ^ ((l >> 2) & 3)) * 8;
  const unsigned short* Asrc = A + (size_t)(m0 + srow) * K + sg8;
  const unsigned short* Bsrc = Bt + (size_t)(n0 + srow) * K + sg8;
  const int aoff = (wr * 128 + lr) * 64 + ((lg ^ (lr & 3)) << 4);
  const int boff = (wc * (BN / 4) + lr) * 64 + ((lg ^ (lr & 3)) << 4);

  auto stageA = [&](int kt) {
    unsigned char* bb = smem + (kt & 3) * BUF;
#pragma unroll
    for (int i = 0; i < 2; i++)
      GLDS16(Asrc + (size_t)i * 128 * K + kt * 32, bb + (i * 512 + w * 64) * 16);
  };
  auto stageB = [&](int kt) {
    unsigned char* bb = smem + (kt & 3) * BUF + ABY;
#pragma unroll
    for (int i = 0; i < BSTMT; i++)
      GLDS16(Bsrc + (size_t)i * 128 * K + kt * 32, bb + (i * 512 + w * 64) * 16);
  };

  f32x4 acc[8][NF] = {};

  for (int kt = 0; kt < 3; kt++) { stageA(kt); stageB(kt); }
  asm volatile("s_waitcnt vmcnt(%0)" ::"i"(2 * VPK) : "memory");
  __builtin_amdgcn_s_barrier();

  for (int kt = 0; kt < nk; kt++) {
    unsigned char* ba = smem + (kt & 3) * BUF;
    unsigned char* bb = ba + ABY;
    const bool st = (kt + 3) < nk;
    if constexpr (BN == 256) {
      bf16x8 am[4], bnf[4];
#pragma unroll
      for (int m = 0; m < 4; m++) am[m] = *(const bf16x8*)(ba + aoff + m * 1024);
#pragma unroll
      for (int n = 0; n < 4; n++) bnf[n] = *(const bf16x8*)(bb + boff + n * 1024);
      if (st) stageA(kt + 3);
      __builtin_amdgcn_s_barrier();
      __builtin_amdgcn_s_setprio(1);
#pragma unroll
      for (int m = 0; m < 4; m++)
#pragma unroll
        for (int n = 0; n < 4; n++)
          acc[m][n] = __builtin_amdgcn_mfma_f32_16x16x32_bf16(am[m], bnf[n], acc[m][n], 0, 0, 0);
      __builtin_amdgcn_s_setprio(0);
      __builtin_amdgcn_s_barrier();
#pragma unroll
      for (int m = 0; m < 4; m++) am[m] = *(const bf16x8*)(ba + aoff + (m + 4) * 1024);
      if (st) stageB(kt + 3);
      __builtin_amdgcn_s_barrier();
      __builtin_amdgcn_s_setprio(1);
#pragma unroll
      for (int m = 0; m < 4; m++)
#pragma unroll
        for (int n = 0; n < 4; n++)
          acc[m + 4][n] = __builtin_amdgcn_mfma_f32_16x16x32_bf16(am[m], bnf[n], acc[m + 4][n], 0, 0, 0);
      __builtin_amdgcn_s_setprio(0);
      if (kt <= nk - 4)      asm volatile("s_waitcnt vmcnt(%0)" ::"i"(2 * VPK) : "memory");
      else if (kt == nk - 3) asm volatile("s_waitcnt vmcnt(%0)" ::"i"(VPK) : "memory");
      else if (kt == nk - 2) asm volatile("s_waitcnt vmcnt(0)" ::: "memory");
      __builtin_amdgcn_s_barrier();
    } else {
      bf16x8 am[8], bnf[2];
#pragma unroll
      for (int m = 0; m < 8; m++) am[m] = *(const bf16x8*)(ba + aoff + m * 1024);
#pragma unroll
      for (int n = 0; n < 2; n++) bnf[n] = *(const bf16x8*)(bb + boff + n * 1024);
      if (st) { stageA(kt + 3); stageB(kt + 3); }
      __builtin_amdgcn_s_barrier();
      __builtin_amdgcn_s_setprio(1);
#pragma unroll
      for (int m = 0; m < 8; m++)
#pragma unroll
        for (int n = 0; n < 2; n++)
          acc[m][n] = __builtin_amdgcn_mfma_f32_16x16x32_bf16(am[m], bnf[n], acc[m][n], 0, 0, 0);
      __builtin_amdgcn_s_setprio(0);
      if (kt <= nk - 4)      asm volatile("s_waitcnt vmcnt(%0)" ::"i"(2 * VPK) : "memory");
      else if (kt == nk - 3) asm volatile("s_waitcnt vmcnt(%0)" ::"i"(VPK) : "memory");
      else if (kt == nk - 2) asm volatile("s_waitcnt vmcnt(0)" ::: "memory");
      __builtin_amdgcn_s_barrier();
    }
  }

  const int rbase = wr * 128 + lg * 4;
  const int cbase = wc * (BN / 4) + lr;
  if constexpr (EPI == 0) {
#pragma unroll
    for (int m = 0; m < 8; m++)
#pragma unroll
      for (int n = 0; n < NF; n++)
#pragma unroll
        for (int j = 0; j < 4; j++)
          outB[(size_t)(m0 + rbase + m * 16 + j) * N + n0 + cbase + n * 16] =
              f2bf(acc[m][n][j]);
  } else if constexpr (EPI == 1) {
#pragma unroll
    for (int m = 0; m < 8; m++)
#pragma unroll
      for (int n = 0; n < NF; n++)
#pragma unroll
        for (int j = 0; j < 4; j++) {
          size_t o = (size_t)(m0 + rbase + m * 16 + j) * N + n0 + cbase + n * 16;
          outF[o] = res[o] + acc[m][n][j];
        }
  } else {
    float* gl = (float*)smem;
    if (wc < 2) {
#pragma unroll
      for (int m = 0; m < 8; m++)
#pragma unroll
        for (int n = 0; n < NF; n++)
#pragma unroll
          for (int j = 0; j < 4; j++)
            gl[(rbase + m * 16 + j) * 128 + wc * 64 + n * 16 + lr] = acc[m][n][j];
    }
    __syncthreads();
    if (wc >= 2) {
      const int ab = n0 >> 1;
#pragma unroll
      for (int m = 0; m < 8; m++)
#pragma unroll
        for (int n = 0; n < NF; n++)
#pragma unroll
          for (int j = 0; j < 4; j++) {
            int rl = rbase + m * 16 + j;
            int cl = (wc - 2) * 64 + n * 16 + lr;
            float g = gl[rl * 128 + cl];
            float s = g / (1.0f + __expf(-g));
            outB[(size_t)(m0 + rl) * FF_ + ab + cl] = f2bf(s * acc[m][n][j]);
          }
    }
  }
}

// ---------------- causal GQA flash attention, 32x32 swapped-QK structure --------------
// Block: 4 waves x 32 q = 128 q rows. KVBLK=64, double-buffered LDS (K 16K + V^T 16K per buf).
// Swapped QK^T: S^T = mfma_32x32x16(K, Q) -> lane owns q = lane&31; kv-reduce is in-lane
// + one shfl_xor(32). P->A-frag via 2 shfl_xor per 16-kv slice. exp2 domain (scale
// pre-folded with log2e in k_rope). Defer-max threshold 11 (=8/ln2). K staged by
// global_load_lds with inverse-swizzled source; V transposed via regs; both read with
// granule ^= (row&7) -> conflict-free ds_read_b128.
__global__ __launch_bounds__(256) void k_attn2(const unsigned short* __restrict__ qkv,
                                               unsigned short* __restrict__ out) {
  __shared__ __attribute__((aligned(16))) unsigned short lK[2][64 * 128];
  __shared__ __attribute__((aligned(16))) unsigned short lV[2][128 * 64];
  const float NEG = -3.0e38f;
  int bx = blockIdx.x;
  int qtile = 15 - (bx >> 5);          // heaviest q-tiles dispatched first
  int hb = bx & 31;
  int h = hb & 15, b = hb >> 4;
  int q0 = qtile * 128;
  int tid = threadIdx.x, w = tid >> 6, l = tid & 63;
  int l31 = l & 31, half2 = l >> 5;
  const unsigned short* base = qkv + (size_t)b * SEQ * 4096;
  const unsigned short* Kp = base + 2048 + (h >> 1) * HD;
  const unsigned short* Vp = base + 3072 + (h >> 1) * HD;
  const int qw = q0 + w * 32;

  // Q fragments (B-operand of swapped QK): lane holds q=qw+l31, d = dblk*16 + 8*half2 + e
  bf16x8 qf[8];
  {
    const unsigned short* qrow = base + (size_t)(qw + l31) * 4096 + h * HD + half2 * 8;
#pragma unroll
    for (int d = 0; d < 8; d++) qf[d] = *(const bf16x8*)(qrow + d * 16);
  }

  f32x16 oacc[4] = {};
  float mrow = NEG, lsum = 0.0f;

  const int vp = tid & 31, vdc = tid >> 5;   // V stage: kv-pair, 16-d chunk
  u16x8 va0, va1, vb0, vb1;

  auto stageK = [&](int t) {
    unsigned char* dst = (unsigned char*)lK[t & 1];
#pragma unroll
    for (int i = 0; i < 4; i++) {
      int c = i * 256 + tid;
      int row = c >> 4;
      int g = (c & 15) ^ (row & 7);          // inverse-swizzled source (rule #21)
      GLDS16(Kp + (size_t)(t * 64 + row) * 4096 + g * 8, dst + (i * 256 + w * 64) * 16);
    }
  };
  auto loadV = [&](int t) {
    const unsigned short* vr = Vp + (size_t)(t * 64 + vp * 2) * 4096 + vdc * 16;
    va0 = *(const u16x8*)(vr);
    va1 = *(const u16x8*)(vr + 8);
    vb0 = *(const u16x8*)(vr + 4096);
    vb1 = *(const u16x8*)(vr + 4096 + 8);
  };

  const int nt = (q0 >> 6) + 2;
  stageK(0);
  loadV(0);

  for (int t = 0; t < nt; t++) {
    __syncthreads();                         // implicit vmcnt(0): K(t) in LDS, V(t) in regs
    {                                        // write V(t) transposed: lV[d][kv], swizzled
      unsigned char* lv = (unsigned char*)lV[t & 1];
#pragma unroll
      for (int j = 0; j < 16; j++) {
        int dd = vdc * 16 + j;
        unsigned short lo = (j < 8) ? va0[j] : va1[j - 8];
        unsigned short hi = (j < 8) ? vb0[j] : vb1[j - 8];
        unsigned int pkv = (unsigned int)lo | ((unsigned int)hi << 16);
        *(unsigned int*)(lv + dd * 128 + (((vp >> 2) ^ (dd & 7)) * 16) + (vp & 3) * 4) = pkv;
      }
    }
    __syncthreads();                         // publish K(t), V(t)
    if (t + 1 < nt) { stageK(t + 1); loadV(t + 1); }  // fly under compute
    const int kv0 = t * 64;
    if (kv0 <= qw + 31) {
      // ---- QK^T: S^T[64 kv][32 q], two 32-kv halves ----
      f32x16 sc[2] = {};
      const unsigned char* lk = (const unsigned char*)lK[t & 1];
#pragma unroll
      for (int hh = 0; hh < 2; hh++) {
        int kk = hh * 32 + l31;
        const unsigned char* krow = lk + kk * 256;
#pragma unroll
        for (int d = 0; d < 8; d++) {
          bf16x8 kf = *(const bf16x8*)(krow + (((d * 2 + half2) ^ (kk & 7)) * 16));
          sc[hh] = __builtin_amdgcn_mfma_f32_32x32x16_bf16(kf, qf[d], sc[hh], 0, 0, 0);
        }
      }
      const int qa = qw + l31;
      if (kv0 + 63 > qw) {                   // causal mask (boundary tiles only)
#pragma unroll
        for (int hh = 0; hh < 2; hh++)
#pragma unroll
          for (int r = 0; r < 16; r++) {
            int kva = kv0 + hh * 32 + (r & 3) + 8 * (r >> 2) + 4 * half2;
            if (kva > qa) sc[hh][r] = NEG;
          }
      }
      // ---- online softmax, lane-local row ----
      float mx = sc[0][0];
#pragma unroll
      for (int r = 1; r < 16; r++) mx = fmaxf(mx, sc[0][r]);
#pragma unroll
      for (int r = 0; r < 16; r++) mx = fmaxf(mx, sc[1][r]);
      mx = fmaxf(mx, __shfl_xor(mx, 32));
      bool ok = (mx <= mrow + 11.0f);        // defer-max (2^11 headroom)
      if (__ballot(ok) != ~0ull) {
        float mnew = fmaxf(mrow, mx);
        float fct = fexp2(mrow - mnew);
        mrow = mnew;
        lsum *= fct;
#pragma unroll
        for (int r = 0; r < 16; r++) {
          int rr = (r & 3) + 8 * (r >> 2) + 4 * half2;
          float fr = __shfl(fct, rr);
#pragma unroll
          for (int d = 0; d < 4; d++) oacc[d][r] *= fr;
        }
      }
      float ps = 0.0f;
#pragma unroll
      for (int hh = 0; hh < 2; hh++)
#pragma unroll
        for (int r = 0; r < 16; r++) {
          float e = fexp2(sc[hh][r] - mrow);
          sc[hh][r] = e;
          ps += e;
        }
      ps += __shfl_xor(ps, 32);
      lsum += ps;
      // ---- PV: O[32 q][128 d] += P[32x64] * V[64x128], 4 kv-slices of 16 ----
      const unsigned char* lv = (const unsigned char*)lV[t & 1];
#pragma unroll
      for (int s = 0; s < 4; s++) {
        const int hh = s >> 1;
        const int r0 = (s & 1) * 8;
        unsigned int lo0, lo1, hi0, hi1;
        if (hh == 0) {
          lo0 = pk2(sc[0][r0 + 0], sc[0][r0 + 1]); lo1 = pk2(sc[0][r0 + 2], sc[0][r0 + 3]);
          hi0 = pk2(sc[0][r0 + 4], sc[0][r0 + 5]); hi1 = pk2(sc[0][r0 + 6], sc[0][r0 + 7]);
        } else {
          lo0 = pk2(sc[1][r0 + 0], sc[1][r0 + 1]); lo1 = pk2(sc[1][r0 + 2], sc[1][r0 + 3]);
          hi0 = pk2(sc[1][r0 + 4], sc[1][r0 + 5]); hi1 = pk2(sc[1][r0 + 6], sc[1][r0 + 7]);
        }
        unsigned int s0 = half2 ? lo0 : hi0, s1 = half2 ? lo1 : hi1;
        unsigned int rc0 = (unsigned int)__shfl_xor((int)s0, 32);
        unsigned int rc1 = (unsigned int)__shfl_xor((int)s1, 32);
        u32x4 fr;
        fr[0] = half2 ? rc0 : lo0; fr[1] = half2 ? rc1 : lo1;
        fr[2] = half2 ? hi0 : rc0; fr[3] = half2 ? hi1 : rc1;
        bf16x8 pa = __builtin_bit_cast(bf16x8, fr);
#pragma unroll
        for (int d = 0; d < 4; d++) {
          int dd = d * 32 + l31;
          bf16x8 vf = *(const bf16x8*)(lv + dd * 128 + (((s * 2 + half2) ^ (dd & 7)) * 16));
          oacc[d] = __builtin_amdgcn_mfma_f32_32x32x16_bf16(pa, vf, oacc[d], 0, 0, 0);
        }
      }
    }
  }
  // ---- epilogue: normalize rows, write O ----
  float inv = 1.0f / lsum;                   // lane's q = qw + l31
#pragma unroll
  for (int r = 0; r < 16; r++) {
    int rr = (r & 3) + 8 * (r >> 2) + 4 * half2;
    float ir = __shfl(inv, rr);
    size_t ob = ((size_t)(b * SEQ + qw + rr)) * 2048 + h * HD;
#pragma unroll
    for (int d = 0; d < 4; d++)
      out[ob + d * 32 + l31] = f2bf(oacc[d][r] * ir);
  }
}

// ---------------- launcher -------------------------------------------------------------
extern "C" void kernel_launch(void* const* d_in, const int* in_sizes, int n_in,
                              void* d_out, int out_size, void* d_ws, size_t ws_size,
                              hipStream_t stream) {
  const float* x = (const float*)d_in[0];
  const float* cosT = (const float*)d_in[1];
  const float* sinT = (const float*)d_in[2];
  const float* wq = (const float*)d_in[3];
  const float* wk = (const float*)d_in[4];
  const float* wv = (const float*)d_in[5];
  const float* wo = (const float*)d_in[6];
  const float* wg = (const float*)d_in[7];
  const float* wu = (const float*)d_in[8];
  const float* wd = (const float*)d_in[9];
  const float* g1 = (const float*)d_in[10];
  const float* g2 = (const float*)d_in[11];
  float* out = (float*)d_out;
  char* ws = (char*)d_ws;

  unsigned short* wqkv = (unsigned short*)(ws + 0);
  unsigned short* hbuf = (unsigned short*)(ws + 16777216);
  unsigned short* qkv = (unsigned short*)(ws + 33554432);
  unsigned short* attn_o = (unsigned short*)(ws + 67108864);
  unsigned short* wo_bf = (unsigned short*)(ws + 83886080);
  unsigned short* wgu = (unsigned short*)(ws + 33554432);
  unsigned short* act = (unsigned short*)(ws + 92274688);
  unsigned short* wdown = (unsigned short*)(ws + 0);

  // ---- attention sub-block ----
  k_conv<<<2048, 256, 0, stream>>>(wq, wqkv);
  k_conv<<<1024, 256, 0, stream>>>(wk, wqkv + 4194304);
  k_conv<<<1024, 256, 0, stream>>>(wv, wqkv + 6291456);
  k_rmsnorm<<<4096, 256, 0, stream>>>(x, g1, hbuf);
  k_gemm8<256, 0><<<256, 512, 0, stream>>>(hbuf, wqkv, qkv, nullptr, nullptr,
                                           4096, 2048);
  k_rope<<<24576, 256, 0, stream>>>(qkv, cosT, sinT);
  k_attn2<<<512, 256, 0, stream>>>(qkv, attn_o);
  k_conv<<<2048, 256, 0, stream>>>(wo, wo_bf);
  k_gemm8<128, 1><<<256, 512, 0, stream>>>(attn_o, wo_bf, nullptr, out, x,
                                           2048, 2048);
  // ---- SwiGLU MLP sub-block ----
  k_rmsnorm<<<4096, 256, 0, stream>>>(out, g2, hbuf);
  k_conv_gu<<<11008, 256, 0, stream>>>(wg, wu, wgu);
  k_gemm8<256, 2><<<688, 512, 0, stream>>>(hbuf, wgu, act, nullptr, nullptr,
                                           11008, 2048);
  k_conv<<<5504, 256, 0, stream>>>(wd, wdown);
  k_gemm8<128, 1><<<256, 512, 0, stream>>>(act, wdown, nullptr, out, out,
                                           2048, 5504);
}

// Round 5
// 613.924 us; speedup vs baseline: 1.4639x; 1.0350x over previous
//
#include <hip/hip_runtime.h>

// LLM block: B=2,S=2048,D=2048,H=16,KVH=8,HD=128,FF=5504, f32 in/out, bf16 MFMA compute.
// Workspace layout (bytes), peak ~137MB:
//   wqkv_bf16   [4096,2048]  @ 0
//   h/h2_bf16   [4096,2048]  @ 16777216
//   qkv_bf16    [4096,4096]  @ 33554432   (region reused later by wgu)
//   attn_out    [4096,2048]  @ 67108864
//   wo_bf16     [2048,2048]  @ 83886080
//   wgu_bf16    [11008,2048] @ 33554432   (interleaved: per 256-row group = 128 gate | 128 up)
//   act_bf16    [4096,5504]  @ 92274688
//   wdown_bf16  [2048,5504]  @ 0
//   x1 (f32 residual) lives in d_out.

#define DM 2048
#define SEQ 2048
#define HD 128
#define FF_ 5504
// 1/sqrt(128) * log2(e): attention runs softmax in exp2 domain.
#define QK_SCALE_L2E 0.12751744f

typedef __bf16 bf16x8 __attribute__((ext_vector_type(8)));
typedef float f32x4 __attribute__((ext_vector_type(4)));
typedef float f32x16 __attribute__((ext_vector_type(16)));
typedef unsigned short u16x8 __attribute__((ext_vector_type(8)));
typedef unsigned int u32x4 __attribute__((ext_vector_type(4)));

typedef __attribute__((address_space(1))) void* gas1;
typedef __attribute__((address_space(3))) void* las3;
#define GLDS16(g, s) __builtin_amdgcn_global_load_lds((gas1)(g), (las3)(s), 16, 0, 0)

static __device__ __forceinline__ float bf2f(unsigned short u) {
  union { unsigned int i; float f; } c; c.i = ((unsigned int)u) << 16; return c.f;
}
static __device__ __forceinline__ unsigned short f2bf(float f) {
  __bf16 b = (__bf16)f;
  return __builtin_bit_cast(unsigned short, b);
}
static __device__ __forceinline__ unsigned int pk2(float a, float b) {
  return (unsigned int)f2bf(a) | ((unsigned int)f2bf(b) << 16);
}
// native exp2 (v_exp_f32); __exp2f doesn't exist in HIP headers (r3 compile fail)
static __device__ __forceinline__ float fexp2(float x) { return exp2f(x); }

// ---------------- f32 -> bf16 convert (8 elems/thread, exact grid) ----------------
__global__ __launch_bounds__(256) void k_conv(const float* __restrict__ src,
                                              unsigned short* __restrict__ dst) {
  size_t i = (size_t)(blockIdx.x * 256 + threadIdx.x) * 8;
  float4 a = *(const float4*)&src[i];
  float4 b = *(const float4*)&src[i + 4];
  u16x8 o;
  o[0] = f2bf(a.x); o[1] = f2bf(a.y); o[2] = f2bf(a.z); o[3] = f2bf(a.w);
  o[4] = f2bf(b.x); o[5] = f2bf(b.y); o[6] = f2bf(b.z); o[7] = f2bf(b.w);
  *(u16x8*)&dst[i] = o;
}

// ---- gate/up interleaved convert: dst row r of group t: r<128 -> wg, else wu ----
__global__ __launch_bounds__(256) void k_conv_gu(const float* __restrict__ g,
                                                 const float* __restrict__ u,
                                                 unsigned short* __restrict__ dst) {
  int i = blockIdx.x * 256 + threadIdx.x;
  int row = i >> 8;
  int c8 = (i & 255) * 8;
  int t = row >> 8, r = row & 255;
  const float* src = (r < 128) ? (g + (size_t)(t * 128 + r) * DM + c8)
                               : (u + (size_t)(t * 128 + (r - 128)) * DM + c8);
  float4 a = *(const float4*)src;
  float4 b = *(const float4*)(src + 4);
  u16x8 o;
  o[0] = f2bf(a.x); o[1] = f2bf(a.y); o[2] = f2bf(a.z); o[3] = f2bf(a.w);
  o[4] = f2bf(b.x); o[5] = f2bf(b.y); o[6] = f2bf(b.z); o[7] = f2bf(b.w);
  *(u16x8*)&dst[(size_t)row * DM + c8] = o;
}

// ---------------- RMSNorm: one block per row (D=2048, 8 f32/thread) ----------------
__global__ __launch_bounds__(256) void k_rmsnorm(const float* __restrict__ x,
                                                 const float* __restrict__ g,
                                                 unsigned short* __restrict__ out) {
  int row = blockIdx.x, tid = threadIdx.x;
  const float* xr = x + (size_t)row * DM;
  float4 a = *(const float4*)&xr[tid * 8];
  float4 b = *(const float4*)&xr[tid * 8 + 4];
  float ss = a.x * a.x + a.y * a.y + a.z * a.z + a.w * a.w +
             b.x * b.x + b.y * b.y + b.z * b.z + b.w * b.w;
#pragma unroll
  for (int off = 32; off > 0; off >>= 1) ss += __shfl_xor(ss, off, 64);
  __shared__ float red[4];
  if ((tid & 63) == 0) red[tid >> 6] = ss;
  __syncthreads();
  float rs = rsqrtf((red[0] + red[1] + red[2] + red[3]) * (1.0f / DM) + 1e-5f);
  float4 ga = *(const float4*)&g[tid * 8];
  float4 gb = *(const float4*)&g[tid * 8 + 4];
  u16x8 o;
  o[0] = f2bf(a.x * rs * ga.x); o[1] = f2bf(a.y * rs * ga.y);
  o[2] = f2bf(a.z * rs * ga.z); o[3] = f2bf(a.w * rs * ga.w);
  o[4] = f2bf(b.x * rs * gb.x); o[5] = f2bf(b.y * rs * gb.y);
  o[6] = f2bf(b.z * rs * gb.z); o[7] = f2bf(b.w * rs * gb.w);
  *(u16x8*)&out[(size_t)row * DM + tid * 8] = o;
}

// ---------------- RoPE in-place on qkv buffer (q cols 0..2047, k cols 2048..3071) ----
__global__ __launch_bounds__(256) void k_rope(unsigned short* __restrict__ qkv,
                                              const float* __restrict__ cosT,
                                              const float* __restrict__ sinT) {
  int idx = blockIdx.x * 256 + threadIdx.x;
  int j = idx & 63;
  int hh = (idx >> 6) % 24;
  int tok = idx / (64 * 24);
  int s = tok & (SEQ - 1);
  int colbase = (hh < 16) ? hh * HD : DM + (hh - 16) * HD;
  unsigned short* p = qkv + (size_t)tok * 4096 + colbase;
  float lo = bf2f(p[j]), hi = bf2f(p[j + 64]);
  const float* cr = cosT + (size_t)s * HD;
  const float* sr = sinT + (size_t)s * HD;
  float nl = lo * cr[j] - hi * sr[j];
  float nh = hi * cr[j + 64] + lo * sr[j + 64];
  if (hh < 16) { nl *= QK_SCALE_L2E; nh *= QK_SCALE_L2E; }  // fold scale*log2e into q
  p[j] = f2bf(nl);
  p[j + 64] = f2bf(nh);
}

// ---------------- deep-pipelined GEMM: C[M,N] = A[M,K] * Bt[N,K]^T --------------------
// BM=256, BK=32, 8 waves (2Mx4N), 4 LDS buffers, counted vmcnt, setprio.
// Bank-conflict-free swizzle (r4 fix): 16B-granule g' = g ^ ((row>>1)&3).
//   Reader bank0 = 16*(lr&1) + 4*(lg^((lr>>1)&3)): each 8-lane group covers all
//   32 banks exactly once (r3's row&3 variant collided lanes lr/lr+4, 1.8e7 conflicts).
// Source pre-swizzled (rule #21: global_load_lds dest is linear), reads swizzled.
template <int BN, int EPI>
__global__ __launch_bounds__(512, 2) void k_gemm8(
    const unsigned short* __restrict__ A, const unsigned short* __restrict__ Bt,
    unsigned short* __restrict__ outB, float* __restrict__ outF,
    const float* __restrict__ res, int N, int K) {
  constexpr int NF = BN / 64;
  constexpr int BSTMT = BN / 128;
  constexpr int ABY = 256 * 64;
  constexpr int BBY = BN * 64;
  constexpr int BUF = ABY + BBY;
  constexpr int VPK = 2 + BSTMT;
  __shared__ __attribute__((aligned(16))) unsigned char smem[4 * BUF];

  const int tid = threadIdx.x, w = tid >> 6, l = tid & 63;
  const int wr = w >> 2, wc = w & 3, lr = l & 15, lg = l >> 4;
  const int nwg = gridDim.x, bid = blockIdx.x;
  const int bswz = (bid & 7) * (nwg >> 3) + (bid >> 3);
  const int mt = bswz & 15, nt = bswz >> 4;
  const int m0 = mt * 256, n0 = nt * BN;
  const int nk = K >> 5;

  const int srow = w * 16 + (l >> 2);
  const int sg8 = ((l & 3) ^ ((l >> 3) & 3)) * 8;         // pre-swizzle: g ^ ((row>>1)&3)
  const unsigned short* Asrc = A + (size_t)(m0 + srow) * K + sg8;
  const unsigned short* Bsrc = Bt + (size_t)(n0 + srow) * K + sg8;
  const int aoff = (wr * 128 + lr) * 64 + ((lg ^ ((lr >> 1) & 3)) << 4);
  const int boff = (wc * (BN / 4) + lr) * 64 + ((lg ^ ((lr >> 1) & 3)) << 4);

  auto stageA = [&](int kt) {
    unsigned char* bb = smem + (kt & 3) * BUF;
#pragma unroll
    for (int i = 0; i < 2; i++)
      GLDS16(Asrc + (size_t)i * 128 * K + kt * 32, bb + (i * 512 + w * 64) * 16);
  };
  auto stageB = [&](int kt) {
    unsigned char* bb = smem + (kt & 3) * BUF + ABY;
#pragma unroll
    for (int i = 0; i < BSTMT; i++)
      GLDS16(Bsrc + (size_t)i * 128 * K + kt * 32, bb + (i * 512 + w * 64) * 16);
  };

  f32x4 acc[8][NF] = {};

  for (int kt = 0; kt < 3; kt++) { stageA(kt); stageB(kt); }
  asm volatile("s_waitcnt vmcnt(%0)" ::"i"(2 * VPK) : "memory");
  __builtin_amdgcn_s_barrier();

  for (int kt = 0; kt < nk; kt++) {
    unsigned char* ba = smem + (kt & 3) * BUF;
    unsigned char* bb = ba + ABY;
    const bool st = (kt + 3) < nk;
    if constexpr (BN == 256) {
      bf16x8 am[4], bnf[4];
#pragma unroll
      for (int m = 0; m < 4; m++) am[m] = *(const bf16x8*)(ba + aoff + m * 1024);
#pragma unroll
      for (int n = 0; n < 4; n++) bnf[n] = *(const bf16x8*)(bb + boff + n * 1024);
      if (st) stageA(kt + 3);
      __builtin_amdgcn_s_barrier();
      __builtin_amdgcn_s_setprio(1);
#pragma unroll
      for (int m = 0; m < 4; m++)
#pragma unroll
        for (int n = 0; n < 4; n++)
          acc[m][n] = __builtin_amdgcn_mfma_f32_16x16x32_bf16(am[m], bnf[n], acc[m][n], 0, 0, 0);
      __builtin_amdgcn_s_setprio(0);
      __builtin_amdgcn_s_barrier();
#pragma unroll
      for (int m = 0; m < 4; m++) am[m] = *(const bf16x8*)(ba + aoff + (m + 4) * 1024);
      if (st) stageB(kt + 3);
      __builtin_amdgcn_s_barrier();
      __builtin_amdgcn_s_setprio(1);
#pragma unroll
      for (int m = 0; m < 4; m++)
#pragma unroll
        for (int n = 0; n < 4; n++)
          acc[m + 4][n] = __builtin_amdgcn_mfma_f32_16x16x32_bf16(am[m], bnf[n], acc[m + 4][n], 0, 0, 0);
      __builtin_amdgcn_s_setprio(0);
      if (kt <= nk - 4)      asm volatile("s_waitcnt vmcnt(%0)" ::"i"(2 * VPK) : "memory");
      else if (kt == nk - 3) asm volatile("s_waitcnt vmcnt(%0)" ::"i"(VPK) : "memory");
      else if (kt == nk - 2) asm volatile("s_waitcnt vmcnt(0)" ::: "memory");
      __builtin_amdgcn_s_barrier();
    } else {
      bf16x8 am[8], bnf[2];
#pragma unroll
      for (int m = 0; m < 8; m++) am[m] = *(const bf16x8*)(ba + aoff + m * 1024);
#pragma unroll
      for (int n = 0; n < 2; n++) bnf[n] = *(const bf16x8*)(bb + boff + n * 1024);
      if (st) { stageA(kt + 3); stageB(kt + 3); }
      __builtin_amdgcn_s_barrier();
      __builtin_amdgcn_s_setprio(1);
#pragma unroll
      for (int m = 0; m < 8; m++)
#pragma unroll
        for (int n = 0; n < 2; n++)
          acc[m][n] = __builtin_amdgcn_mfma_f32_16x16x32_bf16(am[m], bnf[n], acc[m][n], 0, 0, 0);
      __builtin_amdgcn_s_setprio(0);
      if (kt <= nk - 4)      asm volatile("s_waitcnt vmcnt(%0)" ::"i"(2 * VPK) : "memory");
      else if (kt == nk - 3) asm volatile("s_waitcnt vmcnt(%0)" ::"i"(VPK) : "memory");
      else if (kt == nk - 2) asm volatile("s_waitcnt vmcnt(0)" ::: "memory");
      __builtin_amdgcn_s_barrier();
    }
  }

  const int rbase = wr * 128 + lg * 4;
  const int cbase = wc * (BN / 4) + lr;
  if constexpr (EPI == 0) {
#pragma unroll
    for (int m = 0; m < 8; m++)
#pragma unroll
      for (int n = 0; n < NF; n++)
#pragma unroll
        for (int j = 0; j < 4; j++)
          outB[(size_t)(m0 + rbase + m * 16 + j) * N + n0 + cbase + n * 16] =
              f2bf(acc[m][n][j]);
  } else if constexpr (EPI == 1) {
#pragma unroll
    for (int m = 0; m < 8; m++)
#pragma unroll
      for (int n = 0; n < NF; n++)
#pragma unroll
        for (int j = 0; j < 4; j++) {
          size_t o = (size_t)(m0 + rbase + m * 16 + j) * N + n0 + cbase + n * 16;
          outF[o] = res[o] + acc[m][n][j];
        }
  } else {
    float* gl = (float*)smem;
    if (wc < 2) {
#pragma unroll
      for (int m = 0; m < 8; m++)
#pragma unroll
        for (int n = 0; n < NF; n++)
#pragma unroll
          for (int j = 0; j < 4; j++)
            gl[(rbase + m * 16 + j) * 128 + wc * 64 + n * 16 + lr] = acc[m][n][j];
    }
    __syncthreads();
    if (wc >= 2) {
      const int ab = n0 >> 1;
#pragma unroll
      for (int m = 0; m < 8; m++)
#pragma unroll
        for (int n = 0; n < NF; n++)
#pragma unroll
          for (int j = 0; j < 4; j++) {
            int rl = rbase + m * 16 + j;
            int cl = (wc - 2) * 64 + n * 16 + lr;
            float g = gl[rl * 128 + cl];
            float s = g / (1.0f + __expf(-g));
            outB[(size_t)(m0 + rl) * FF_ + ab + cl] = f2bf(s * acc[m][n][j]);
          }
    }
  }
}

// ---------------- causal GQA flash attention, 32x32 swapped-QK structure --------------
// Block: 4 waves x 32 q = 128 q rows. KVBLK=64, double-buffered LDS (K 16K + V^T 16K per buf).
// Swapped QK^T: S^T = mfma_32x32x16(K, Q) -> lane owns q = lane&31; kv-reduce is in-lane
// + one shfl_xor(32). P->A-frag via 2 shfl_xor per 16-kv slice. exp2 domain (scale
// pre-folded with log2e in k_rope). Defer-max threshold 11 (=8/ln2). K staged by
// global_load_lds with inverse-swizzled source; V transposed via regs; both read with
// granule ^= (row&7) -> conflict-free ds_read_b128.
__global__ __launch_bounds__(256) void k_attn2(const unsigned short* __restrict__ qkv,
                                               unsigned short* __restrict__ out) {
  __shared__ __attribute__((aligned(16))) unsigned short lK[2][64 * 128];
  __shared__ __attribute__((aligned(16))) unsigned short lV[2][128 * 64];
  const float NEG = -3.0e38f;
  int bx = blockIdx.x;
  int qtile = 15 - (bx >> 5);          // heaviest q-tiles dispatched first
  int hb = bx & 31;
  int h = hb & 15, b = hb >> 4;
  int q0 = qtile * 128;
  int tid = threadIdx.x, w = tid >> 6, l = tid & 63;
  int l31 = l & 31, half2 = l >> 5;
  const unsigned short* base = qkv + (size_t)b * SEQ * 4096;
  const unsigned short* Kp = base + 2048 + (h >> 1) * HD;
  const unsigned short* Vp = base + 3072 + (h >> 1) * HD;
  const int qw = q0 + w * 32;

  // Q fragments (B-operand of swapped QK): lane holds q=qw+l31, d = dblk*16 + 8*half2 + e
  bf16x8 qf[8];
  {
    const unsigned short* qrow = base + (size_t)(qw + l31) * 4096 + h * HD + half2 * 8;
#pragma unroll
    for (int d = 0; d < 8; d++) qf[d] = *(const bf16x8*)(qrow + d * 16);
  }

  f32x16 oacc[4] = {};
  float mrow = NEG, lsum = 0.0f;

  const int vp = tid & 31, vdc = tid >> 5;   // V stage: kv-pair, 16-d chunk
  u16x8 va0, va1, vb0, vb1;

  auto stageK = [&](int t) {
    unsigned char* dst = (unsigned char*)lK[t & 1];
#pragma unroll
    for (int i = 0; i < 4; i++) {
      int c = i * 256 + tid;
      int row = c >> 4;
      int g = (c & 15) ^ (row & 7);          // inverse-swizzled source (rule #21)
      GLDS16(Kp + (size_t)(t * 64 + row) * 4096 + g * 8, dst + (i * 256 + w * 64) * 16);
    }
  };
  auto loadV = [&](int t) {
    const unsigned short* vr = Vp + (size_t)(t * 64 + vp * 2) * 4096 + vdc * 16;
    va0 = *(const u16x8*)(vr);
    va1 = *(const u16x8*)(vr + 8);
    vb0 = *(const u16x8*)(vr + 4096);
    vb1 = *(const u16x8*)(vr + 4096 + 8);
  };

  const int nt = (q0 >> 6) + 2;
  stageK(0);
  loadV(0);

  for (int t = 0; t < nt; t++) {
    __syncthreads();                         // implicit vmcnt(0): K(t) in LDS, V(t) in regs
    {                                        // write V(t) transposed: lV[d][kv], swizzled
      unsigned char* lv = (unsigned char*)lV[t & 1];
#pragma unroll
      for (int j = 0; j < 16; j++) {
        int dd = vdc * 16 + j;
        unsigned short lo = (j < 8) ? va0[j] : va1[j - 8];
        unsigned short hi = (j < 8) ? vb0[j] : vb1[j - 8];
        unsigned int pkv = (unsigned int)lo | ((unsigned int)hi << 16);
        *(unsigned int*)(lv + dd * 128 + (((vp >> 2) ^ (dd & 7)) * 16) + (vp & 3) * 4) = pkv;
      }
    }
    __syncthreads();                         // publish K(t), V(t)
    if (t + 1 < nt) { stageK(t + 1); loadV(t + 1); }  // fly under compute
    const int kv0 = t * 64;
    if (kv0 <= qw + 31) {
      // ---- QK^T: S^T[64 kv][32 q], two 32-kv halves ----
      f32x16 sc[2] = {};
      const unsigned char* lk = (const unsigned char*)lK[t & 1];
#pragma unroll
      for (int hh = 0; hh < 2; hh++) {
        int kk = hh * 32 + l31;
        const unsigned char* krow = lk + kk * 256;
#pragma unroll
        for (int d = 0; d < 8; d++) {
          bf16x8 kf = *(const bf16x8*)(krow + (((d * 2 + half2) ^ (kk & 7)) * 16));
          sc[hh] = __builtin_amdgcn_mfma_f32_32x32x16_bf16(kf, qf[d], sc[hh], 0, 0, 0);
        }
      }
      const int qa = qw + l31;
      if (kv0 + 63 > qw) {                   // causal mask (boundary tiles only)
#pragma unroll
        for (int hh = 0; hh < 2; hh++)
#pragma unroll
          for (int r = 0; r < 16; r++) {
            int kva = kv0 + hh * 32 + (r & 3) + 8 * (r >> 2) + 4 * half2;
            if (kva > qa) sc[hh][r] = NEG;
          }
      }
      // ---- online softmax, lane-local row ----
      float mx = sc[0][0];
#pragma unroll
      for (int r = 1; r < 16; r++) mx = fmaxf(mx, sc[0][r]);
#pragma unroll
      for (int r = 0; r < 16; r++) mx = fmaxf(mx, sc[1][r]);
      mx = fmaxf(mx, __shfl_xor(mx, 32));
      bool ok = (mx <= mrow + 11.0f);        // defer-max (2^11 headroom)
      if (__ballot(ok) != ~0ull) {
        float mnew = fmaxf(mrow, mx);
        float fct = fexp2(mrow - mnew);
        mrow = mnew;
        lsum *= fct;
#pragma unroll
        for (int r = 0; r < 16; r++) {
          int rr = (r & 3) + 8 * (r >> 2) + 4 * half2;
          float fr = __shfl(fct, rr);
#pragma unroll
          for (int d = 0; d < 4; d++) oacc[d][r] *= fr;
        }
      }
      float ps = 0.0f;
#pragma unroll
      for (int hh = 0; hh < 2; hh++)
#pragma unroll
        for (int r = 0; r < 16; r++) {
          float e = fexp2(sc[hh][r] - mrow);
          sc[hh][r] = e;
          ps += e;
        }
      ps += __shfl_xor(ps, 32);
      lsum += ps;
      // ---- PV: O[32 q][128 d] += P[32x64] * V[64x128], 4 kv-slices of 16 ----
      const unsigned char* lv = (const unsigned char*)lV[t & 1];
#pragma unroll
      for (int s = 0; s < 4; s++) {
        const int hh = s >> 1;
        const int r0 = (s & 1) * 8;
        unsigned int lo0, lo1, hi0, hi1;
        if (hh == 0) {
          lo0 = pk2(sc[0][r0 + 0], sc[0][r0 + 1]); lo1 = pk2(sc[0][r0 + 2], sc[0][r0 + 3]);
          hi0 = pk2(sc[0][r0 + 4], sc[0][r0 + 5]); hi1 = pk2(sc[0][r0 + 6], sc[0][r0 + 7]);
        } else {
          lo0 = pk2(sc[1][r0 + 0], sc[1][r0 + 1]); lo1 = pk2(sc[1][r0 + 2], sc[1][r0 + 3]);
          hi0 = pk2(sc[1][r0 + 4], sc[1][r0 + 5]); hi1 = pk2(sc[1][r0 + 6], sc[1][r0 + 7]);
        }
        unsigned int s0 = half2 ? lo0 : hi0, s1 = half2 ? lo1 : hi1;
        unsigned int rc0 = (unsigned int)__shfl_xor((int)s0, 32);
        unsigned int rc1 = (unsigned int)__shfl_xor((int)s1, 32);
        u32x4 fr;
        fr[0] = half2 ? rc0 : lo0; fr[1] = half2 ? rc1 : lo1;
        fr[2] = half2 ? hi0 : rc0; fr[3] = half2 ? hi1 : rc1;
        bf16x8 pa = __builtin_bit_cast(bf16x8, fr);
#pragma unroll
        for (int d = 0; d < 4; d++) {
          int dd = d * 32 + l31;
          bf16x8 vf = *(const bf16x8*)(lv + dd * 128 + (((s * 2 + half2) ^ (dd & 7)) * 16));
          oacc[d] = __builtin_amdgcn_mfma_f32_32x32x16_bf16(pa, vf, oacc[d], 0, 0, 0);
        }
      }
    }
  }
  // ---- epilogue: normalize rows, write O ----
  float inv = 1.0f / lsum;                   // lane's q = qw + l31
#pragma unroll
  for (int r = 0; r < 16; r++) {
    int rr = (r & 3) + 8 * (r >> 2) + 4 * half2;
    float ir = __shfl(inv, rr);
    size_t ob = ((size_t)(b * SEQ + qw + rr)) * 2048 + h * HD;
#pragma unroll
    for (int d = 0; d < 4; d++)
      out[ob + d * 32 + l31] = f2bf(oacc[d][r] * ir);
  }
}

// ---------------- launcher -------------------------------------------------------------
extern "C" void kernel_launch(void* const* d_in, const int* in_sizes, int n_in,
                              void* d_out, int out_size, void* d_ws, size_t ws_size,
                              hipStream_t stream) {
  const float* x = (const float*)d_in[0];
  const float* cosT = (const float*)d_in[1];
  const float* sinT = (const float*)d_in[2];
  const float* wq = (const float*)d_in[3];
  const float* wk = (const float*)d_in[4];
  const float* wv = (const float*)d_in[5];
  const float* wo = (const float*)d_in[6];
  const float* wg = (const float*)d_in[7];
  const float* wu = (const float*)d_in[8];
  const float* wd = (const float*)d_in[9];
  const float* g1 = (const float*)d_in[10];
  const float* g2 = (const float*)d_in[11];
  float* out = (float*)d_out;
  char* ws = (char*)d_ws;

  unsigned short* wqkv = (unsigned short*)(ws + 0);
  unsigned short* hbuf = (unsigned short*)(ws + 16777216);
  unsigned short* qkv = (unsigned short*)(ws + 33554432);
  unsigned short* attn_o = (unsigned short*)(ws + 67108864);
  unsigned short* wo_bf = (unsigned short*)(ws + 83886080);
  unsigned short* wgu = (unsigned short*)(ws + 33554432);
  unsigned short* act = (unsigned short*)(ws + 92274688);
  unsigned short* wdown = (unsigned short*)(ws + 0);

  // ---- attention sub-block ----
  k_conv<<<2048, 256, 0, stream>>>(wq, wqkv);
  k_conv<<<1024, 256, 0, stream>>>(wk, wqkv + 4194304);
  k_conv<<<1024, 256, 0, stream>>>(wv, wqkv + 6291456);
  k_rmsnorm<<<4096, 256, 0, stream>>>(x, g1, hbuf);
  k_gemm8<256, 0><<<256, 512, 0, stream>>>(hbuf, wqkv, qkv, nullptr, nullptr,
                                           4096, 2048);
  k_rope<<<24576, 256, 0, stream>>>(qkv, cosT, sinT);
  k_attn2<<<512, 256, 0, stream>>>(qkv, attn_o);
  k_conv<<<2048, 256, 0, stream>>>(wo, wo_bf);
  k_gemm8<128, 1><<<256, 512, 0, stream>>>(attn_o, wo_bf, nullptr, out, x,
                                           2048, 2048);
  // ---- SwiGLU MLP sub-block ----
  k_rmsnorm<<<4096, 256, 0, stream>>>(out, g2, hbuf);
  k_conv_gu<<<11008, 256, 0, stream>>>(wg, wu, wgu);
  k_gemm8<256, 2><<<688, 512, 0, stream>>>(hbuf, wgu, act, nullptr, nullptr,
                                           11008, 2048);
  k_conv<<<5504, 256, 0, stream>>>(wd, wdown);
  k_gemm8<128, 1><<<256, 512, 0, stream>>>(act, wdown, nullptr, out, out,
                                           2048, 5504);
}